// Round 7
// baseline (331.462 us; speedup 1.0000x reference)
//
#include <hip/hip_runtime.h>
#include <stdint.h>

#define TSEQ 2048
#define NB   4
#define NH   16
#define HD   64
#define EMB  1024
#define ROWS (TSEQ*NB)   // 8192
#define NKT  (EMB/64)    // 16 K-tiles for the projection GEMM
#define PREP_BLOCKS 28672

typedef __attribute__((ext_vector_type(8))) short bf16x8;
typedef __attribute__((ext_vector_type(4))) short bf16x4;
typedef __attribute__((ext_vector_type(4))) float f32x4;

__device__ __forceinline__ short f2bf(float x) {
    uint32_t u = __builtin_bit_cast(uint32_t, x);
    u += 0x7fffu + ((u >> 16) & 1u);     // RNE
    return (short)(u >> 16);
}

__device__ __forceinline__ uint32_t pack2bf(float a, float b) {
    uint32_t ua = __builtin_bit_cast(uint32_t, a) + 0x8000u;
    uint32_t ub = __builtin_bit_cast(uint32_t, b) + 0x8000u;
    return (ua >> 16) | (ub & 0xffff0000u);
}

// async global->LDS, 16B per lane; lds ptr must be wave-uniform (lane i lands at lds + i*16)
__device__ __forceinline__ void gld16(const void* g, void* l) {
    __builtin_amdgcn_global_load_lds(
        (const __attribute__((address_space(1))) void*)g,
        (__attribute__((address_space(3))) void*)l,
        16, 0, 0);
}

// ---------------- prep + scan fused ----------------
// blocks [0, PREP_BLOCKS): fp32->bf16 conversion of [Wq,Wk,Wv,Wo | q,k,v].
// blocks [PREP_BLOCKS, PREP_BLOCKS+NB): per-batch key compaction scan ->
// idxc[b][i] = t of i-th valid key, inv[b][t] = i (or -1 masked),
// bias_c (-12 valid / -1e9 pad), npad[b].
__global__ __launch_bounds__(256)
void prep_scan(const float* __restrict__ q, const float* __restrict__ k, const float* __restrict__ v,
               const float* __restrict__ Wq, const float* __restrict__ Wk,
               const float* __restrict__ Wv, const float* __restrict__ Wo,
               short* __restrict__ Wbf,
               short* __restrict__ Xq, short* __restrict__ Xk, short* __restrict__ Xv,
               const int* __restrict__ mask, int* __restrict__ idxc, int* __restrict__ inv,
               float* __restrict__ bias_c, int* __restrict__ npad)
{
    __shared__ int sums[256];
    __shared__ int totalv;
    const int bid = blockIdx.x, tid = threadIdx.x;

    if (bid < PREP_BLOCKS) {
        int gid = bid * 256 + tid;
        const float4* s4;
        bf16x4* d4;
        if (gid < (1 << 20)) {
            int wsel = gid >> 18;
            const float* src = (wsel == 0) ? Wq : (wsel == 1) ? Wk : (wsel == 2) ? Wv : Wo;
            s4 = (const float4*)src + (gid & ((1 << 18) - 1));
            d4 = (bf16x4*)Wbf + gid;
        } else {
            int iid = gid - (1 << 20);
            int isel = iid >> 21, o = iid & ((1 << 21) - 1);
            const float* src = (isel == 0) ? q : (isel == 1) ? k : v;
            short* dst = (isel == 0) ? Xq : (isel == 1) ? Xk : Xv;
            s4 = (const float4*)src + o;
            d4 = (bf16x4*)dst + o;
        }
        float4 vv = *s4;
        bf16x4 o4 = { f2bf(vv.x), f2bf(vv.y), f2bf(vv.z), f2bf(vv.w) };
        *d4 = o4;
        return;
    }

    // ---- scan part ----
    const int b = bid - PREP_BLOCKS;
    const int* mb = mask + b * TSEQ;
    int valid[8]; int cnt = 0;
    #pragma unroll
    for (int j = 0; j < 8; j++) { valid[j] = (mb[tid * 8 + j] == 0); cnt += valid[j]; }
    sums[tid] = cnt;
    __syncthreads();
    for (int off = 1; off < 256; off <<= 1) {   // Hillis-Steele inclusive scan
        int vv = (tid >= off) ? sums[tid - off] : 0;
        __syncthreads();
        sums[tid] += vv;
        __syncthreads();
    }
    if (tid == 255) totalv = sums[255];
    int base = sums[tid] - cnt;
    __syncthreads();
    int nv = totalv;
    #pragma unroll
    for (int j = 0; j < 8; j++) {
        int t = tid * 8 + j;
        if (valid[j]) { idxc[b * TSEQ + base] = t; inv[b * TSEQ + t] = base; base++; }
        else          { inv[b * TSEQ + t] = -1; }
    }
    for (int i = tid; i < TSEQ; i += 256) {
        if (i >= nv) idxc[b * TSEQ + i] = 0;
        bias_c[b * TSEQ + i] = (i < nv) ? -12.0f : -1e9f;
    }
    if (tid == 0) npad[b] = (nv + 63) & ~63;
}

// ---------------- projection GEMM: 256x256 tile, snake 4-phase schedule ----------------
// C = X @ W^T, all bf16. 512 threads = 8 waves (2M x 4N, interleaved ownership).
// MEASURED-BEST CONFIG (round-3 proposal, proj=67.5us, WRITE=41MB):
//   dense sequential staging (idxc-gathered staging = latency-bound, -10%);
//   z=1 K epilogue scatter-compacts rows via inv (full-line writes: lanes span dk);
//   z=0/z=2 dense epilogue (V transpose scatter = write-amplification, -20%);
//   separate gather_v kernel is CHEAPER than fusing V-transpose here.
// Snake quadrant order (0,0)->(0,1)->(1,1)->(1,0): each phase reads ONE fresh operand
// subtile, holding the other in regs -> 24 ds_read/K-tile. One counted vmcnt(4)/K-tile.
// Register budget: acc fills 128 AGPRs; fragment live-set must stay <=128 VGPRs
// (launch_bounds(512,2) cap) -- deeper pipelining spills (round-3 regression).
// LDS XOR-swizzle byte ^= (row&7)<<4: pre-swizzled global src + swizzled ds_read.

#define DSA(MH)                                                                     \
    _Pragma("unroll")                                                               \
    for (int mf = 0; mf < 4; mf++) {                                                \
        _Pragma("unroll")                                                           \
        for (int ks = 0; ks < 2; ks++) {                                            \
            const int rr = wm*64 + mf*16 + c;                                       \
            const int cb = (ks*64 + g*16) ^ ((rr & 7) << 4);                        \
            af[mf][ks] = *(const bf16x8*)(&lds[cur][0][MH][0] + rr*64 + (cb >> 1)); \
        }                                                                           \
    }

#define DSB(NH_, DST)                                                               \
    _Pragma("unroll")                                                               \
    for (int nf = 0; nf < 2; nf++) {                                                \
        _Pragma("unroll")                                                           \
        for (int ks = 0; ks < 2; ks++) {                                            \
            const int rr = wn*32 + nf*16 + c;                                       \
            const int cb = (ks*64 + g*16) ^ ((rr & 7) << 4);                        \
            DST[nf][ks] = *(const bf16x8*)(&lds[cur][1][NH_][0] + rr*64 + (cb >> 1));\
        }                                                                           \
    }

#define MM(MH, NH_, BREG)                                                           \
    __builtin_amdgcn_s_barrier();                                                   \
    asm volatile("s_waitcnt lgkmcnt(0)" ::: "memory");                              \
    __builtin_amdgcn_sched_barrier(0);                                              \
    __builtin_amdgcn_s_setprio(1);                                                  \
    _Pragma("unroll")                                                               \
    for (int mf = 0; mf < 4; mf++) {                                                \
        _Pragma("unroll")                                                           \
        for (int nf = 0; nf < 2; nf++) {                                            \
            acc[MH][NH_][mf][nf] = __builtin_amdgcn_mfma_f32_16x16x32_bf16(         \
                af[mf][0], BREG[nf][0], acc[MH][NH_][mf][nf], 0, 0, 0);             \
            acc[MH][NH_][mf][nf] = __builtin_amdgcn_mfma_f32_16x16x32_bf16(         \
                af[mf][1], BREG[nf][1], acc[MH][NH_][mf][nf], 0, 0, 0);             \
        }                                                                           \
    }                                                                               \
    __builtin_amdgcn_s_setprio(0);                                                  \
    __builtin_amdgcn_sched_barrier(0);

__global__ __launch_bounds__(512, 2)
void proj_gemm8(const short* __restrict__ Xq, const short* __restrict__ Xk, const short* __restrict__ Xv,
                const short* __restrict__ Wbf, const int* __restrict__ inv,
                short* __restrict__ Qw, short* __restrict__ Kc, short* __restrict__ Vw)
{
    __shared__ __align__(16) short lds[2][2][2][128*64];   // [buf][A/B][half][row*64+col]
    const int z = blockIdx.z;
    const short* __restrict__ A  = (z == 0) ? Xq : (z == 1) ? Xk : Xv;
    const short* __restrict__ Bw = Wbf + (size_t)z * (EMB*EMB);
    short* __restrict__ dst = (z == 0) ? Qw : (z == 1) ? Kc : Vw;
    // Q scale: 1/sqrt(64) * log2(e)  (attention softmax runs in exp2 domain)
    const float scale = (z == 0) ? 0.18033688011112042f : 1.0f;

    const int tid = threadIdx.x;
    const int lane = tid & 63, w = tid >> 6;
    const int wm = w >> 2, wn = w & 3;          // wave owns rows {wm*64, 128+wm*64}, cols {wn*32, 128+wn*32}
    const int g = lane >> 4, c = lane & 15;
    const int m0 = blockIdx.x * 256, n0 = blockIdx.y * 256;

    const short* a0 = A  + (size_t)m0 * EMB;           // A half0: rows m0..m0+127
    const short* a1 = a0 + (size_t)128 * EMB;          // A half1
    const short* b0 = Bw + (size_t)n0 * EMB;           // B half0: W rows n0..n0+127
    const short* b1 = b0 + (size_t)128 * EMB;

    // stage one half-tile (128 rows x 64 cols bf16) cooperatively: 2 gld16 per thread.
    // LDS dest is linear (wave-uniform base + lane*16); source is pre-swizzled so that
    // the ds_read-side XOR (row&7)<<4 recovers the logical element (rule #21).
    auto stage = [&](const short* grow, short* lhalf) {
        #pragma unroll
        for (int p = 0; p < 2; p++) {
            const int lin = p * 8192 + w * 1024 + lane * 16;     // byte offset in half
            const int rin = lin >> 7;                            // row 0..127
            const int cb  = (lin & 127) ^ ((rin & 7) << 4);      // swizzled source col (bytes)
            gld16(grow + (size_t)rin * EMB + (cb >> 1), lhalf + p * 4096 + w * 512);
        }
    };

    // prologue: K-tile 0 fully + A0/B0 of K-tile 1 (matches steady-state issue pattern)
    stage(a0,      &lds[0][0][0][0]);
    stage(a1,      &lds[0][0][1][0]);
    stage(b0,      &lds[0][1][0][0]);
    stage(b1,      &lds[0][1][1][0]);
    stage(a0 + 64, &lds[1][0][0][0]);
    stage(b0 + 64, &lds[1][1][0][0]);
    asm volatile("s_waitcnt vmcnt(4)" ::: "memory");
    __builtin_amdgcn_s_barrier();

    f32x4 acc[2][2][4][2] = {};   // [mh][nh][mf][nf]

    // Phase stages: p0 -> A1[t+1], p1 -> B1[t+1], p2 -> A0[t+2], p3 -> B0[t+2].
    // vmcnt(4) at p3 leaves only {A0[t+2], B0[t+2]} in flight -> all of t+1 landed.
    #pragma unroll 2
    for (int t = 0; t < NKT; t++) {
        const int cur = t & 1, nxt = cur ^ 1;
        const int k1 = (t + 1 < NKT ? t + 1 : NKT - 1) * 64;   // clamped tail stages are
        const int k2 = (t + 2 < NKT ? t + 2 : NKT - 1) * 64;   // redundant writes, harmless
        bf16x8 af[4][2], b0r[2][2], b1r[2][2];
        // p0: quadrant (0,0) — fresh A0 + B0
        DSA(0); DSB(0, b0r);
        stage(a1 + k1, &lds[nxt][0][1][0]);
        MM(0, 0, b0r)
        __builtin_amdgcn_s_barrier();
        // p1: quadrant (0,1) — reuse A0, fresh B1
        DSB(1, b1r);
        stage(b1 + k1, &lds[nxt][1][1][0]);
        MM(0, 1, b1r)
        __builtin_amdgcn_s_barrier();
        // p2: quadrant (1,1) — fresh A1, reuse B1
        DSA(1);
        stage(a0 + k2, &lds[cur][0][0][0]);
        MM(1, 1, b1r)
        __builtin_amdgcn_s_barrier();
        // p3: quadrant (1,0) — reuse A1 + B0 (pure-MFMA phase)
        stage(b0 + k2, &lds[cur][1][0][0]);
        MM(1, 0, b0r)
        asm volatile("s_waitcnt vmcnt(4)" ::: "memory");
        __builtin_amdgcn_s_barrier();
    }
    asm volatile("s_waitcnt vmcnt(0)" ::: "memory");

    // epilogue: permuted store to (B,H,T,64) bf16.
    // z==1: scatter rows through inv[b][t] (compacted K); masked rows skipped.
    if (z == 1) {
        #pragma unroll
        for (int mh = 0; mh < 2; mh++)
            #pragma unroll
            for (int nh = 0; nh < 2; nh++)
                #pragma unroll
                for (int mf = 0; mf < 4; mf++)
                    #pragma unroll
                    for (int nf = 0; nf < 2; nf++)
                        #pragma unroll
                        for (int r = 0; r < 4; r++) {
                            int row = m0 + mh*128 + wm*64 + mf*16 + g*4 + r;
                            int col = n0 + nh*128 + wn*32 + nf*16 + c;
                            int tq = row >> 2, bb = row & 3, h = col >> 6, dk = col & 63;
                            int i = inv[bb * TSEQ + tq];
                            if (i >= 0)
                                dst[(((size_t)(bb*16 + h) * TSEQ + i) << 6) + dk]
                                    = f2bf(acc[mh][nh][mf][nf][r]);
                        }
    } else {
        #pragma unroll
        for (int mh = 0; mh < 2; mh++)
            #pragma unroll
            for (int nh = 0; nh < 2; nh++)
                #pragma unroll
                for (int mf = 0; mf < 4; mf++)
                    #pragma unroll
                    for (int nf = 0; nf < 2; nf++)
                        #pragma unroll
                        for (int r = 0; r < 4; r++) {
                            int row = m0 + mh*128 + wm*64 + mf*16 + g*4 + r;
                            int col = n0 + nh*128 + wn*32 + nf*16 + c;
                            int tq = row >> 2, bb = row & 3, h = col >> 6, dk = col & 63;
                            dst[(((size_t)(bb*16 + h) * TSEQ + tq) << 6) + dk]
                                = f2bf(acc[mh][nh][mf][nf][r] * scale);
                        }
    }
}

// ---------------- gather: V compaction + transpose (K handled in proj epilogue) ----------------
__global__ __launch_bounds__(256)
void gather_v(const short* __restrict__ V,
              const int* __restrict__ idxc, const int* __restrict__ npad,
              short* __restrict__ Vtc)
{
    const int bh = blockIdx.y, b = bh >> 4;
    const int i0 = blockIdx.x * 64;
    if (i0 >= npad[b]) return;
    __shared__ __align__(16) short tile[64*72];
    __shared__ int sidx[64];
    const int tid = threadIdx.x;
    if (tid < 64) sidx[tid] = idxc[b * TSEQ + i0 + tid];
    __syncthreads();
    const short* __restrict__ Vh = V + (size_t)bh * TSEQ * HD;
    #pragma unroll
    for (int p = 0; p < 2; p++) {
        int idx = tid + p * 256, row = idx >> 3, cc = idx & 7;
        int src = sidx[row];
        *(int4*)(&tile[row * 72 + cc * 8]) = *(const int4*)(Vh + (size_t)src * HD + cc * 8);
    }
    __syncthreads();
    #pragma unroll
    for (int p = 0; p < 2; p++) {
        int idx = tid + p * 256, dv = idx >> 3, cc = idx & 7;
        bf16x8 o;
        #pragma unroll
        for (int j = 0; j < 8; j++) o[j] = tile[(cc * 8 + j) * 72 + dv];
        *(bf16x8*)(Vtc + ((size_t)bh * HD + dv) * TSEQ + i0 + cc * 8) = o;
    }
}

// ---------------- flash attention v5: compacted keys, dynamic per-batch bound ----------------
// Occupancy 3 -> 4 blocks/CU (LDS 37.1KB x4 = 148.5KB <= 160KB): +33% TLP to cover the
// serial QK->softmax->LDS->PV chain. VGPR cap drops to 128 -- watch for spill regression.
__global__ __launch_bounds__(256, 4)
void attn_kernel(const short* __restrict__ Q, const short* __restrict__ K,
                 const short* __restrict__ Vt, const float* __restrict__ bias,
                 const int* __restrict__ npad,
                 short* __restrict__ O)
{
    __shared__ __align__(16) short Ks [64*72];    // [tk][d]
    __shared__ __align__(16) short Vts[64*72];    // [dv][tk]
    __shared__ __align__(16) short Ps [128*72];   // [q_local][tk]
    __shared__ __align__(16) float bias_lds[64];

    const int bh = blockIdx.y;
    const int b_ = bh >> 4, h_ = bh & 15;
    const int q0 = blockIdx.x * 128;
    const int tid = threadIdx.x, lane = tid & 63, wv = tid >> 6;
    const int g = lane >> 4, c = lane & 15;
    const int qb = wv * 32;
    const short* __restrict__ Qh  = Q  + (size_t)bh * TSEQ * HD;
    const short* __restrict__ Kh  = K  + (size_t)bh * TSEQ * HD;
    const short* __restrict__ Vth = Vt + (size_t)bh * HD * TSEQ;
    const float* __restrict__ biasb = bias + b_ * TSEQ;
    const int nit = npad[b_] >> 6;   // compacted+padded key count / 64

    const int srow = tid >> 3, scc = tid & 7;

    *(int4*)(&Ks [ srow       * 72 + scc * 8]) = *(const int4*)(Kh  + (size_t) srow       * HD + scc * 8);
    *(int4*)(&Ks [(srow + 32) * 72 + scc * 8]) = *(const int4*)(Kh  + (size_t)(srow + 32) * HD + scc * 8);
    *(int4*)(&Vts[ srow       * 72 + scc * 8]) = *(const int4*)(Vth + (size_t) srow       * TSEQ + scc * 8);
    *(int4*)(&Vts[(srow + 32) * 72 + scc * 8]) = *(const int4*)(Vth + (size_t)(srow + 32) * TSEQ + scc * 8);
    if (tid < 16) ((float4*)bias_lds)[tid] = ((const float4*)biasb)[tid];

    bf16x8 qf[2][2];
    #pragma unroll
    for (int j = 0; j < 2; j++)
        #pragma unroll
        for (int ks = 0; ks < 2; ks++)
            qf[j][ks] = *(const bf16x8*)(Qh + (size_t)(q0 + qb + j * 16 + c) * HD + ks * 32 + g * 8);
    __syncthreads();

    float lacc[2] = { 0.0f, 0.0f };
    f32x4 oacc[2][4] = {};

    for (int it = 0; it < nit; it++) {
        f32x4 sacc[2][4];
        #pragma unroll
        for (int mt = 0; mt < 4; mt++) {
            f32x4 bv = *(const f32x4*)(&bias_lds[mt * 16 + g * 4]);
            sacc[0][mt] = bv; sacc[1][mt] = bv;
        }

        int4 kr0, kr1, vr0, vr1; float4 br;
        const bool pfv = (it + 1 < nit);
        if (pfv) {
            int tk0n = (it + 1) * 64;
            kr0 = *(const int4*)(Kh  + (size_t)(tk0n + srow)      * HD + scc * 8);
            kr1 = *(const int4*)(Kh  + (size_t)(tk0n + srow + 32) * HD + scc * 8);
            vr0 = *(const int4*)(Vth + (size_t) srow       * TSEQ + tk0n + scc * 8);
            vr1 = *(const int4*)(Vth + (size_t)(srow + 32) * TSEQ + tk0n + scc * 8);
            if (tid < 16) br = ((const float4*)(biasb + tk0n))[tid];
        }

        __builtin_amdgcn_s_setprio(1);
        #pragma unroll
        for (int ks = 0; ks < 2; ks++)
            #pragma unroll
            for (int mt = 0; mt < 4; mt++) {
                bf16x8 kf = *(const bf16x8*)(&Ks[(mt * 16 + c) * 72 + ks * 32 + g * 8]);
                sacc[0][mt] = __builtin_amdgcn_mfma_f32_16x16x32_bf16(kf, qf[0][ks], sacc[0][mt], 0, 0, 0);
                sacc[1][mt] = __builtin_amdgcn_mfma_f32_16x16x32_bf16(kf, qf[1][ks], sacc[1][mt], 0, 0, 0);
            }
        __builtin_amdgcn_s_setprio(0);

        #pragma unroll
        for (int j = 0; j < 2; j++) {
            int prow = (qb + j * 16 + c) * 72;
            float lp = 0.0f;
            #pragma unroll
            for (int mt = 0; mt < 4; mt++) {
                float e0 = __builtin_amdgcn_exp2f(sacc[j][mt][0]);
                float e1 = __builtin_amdgcn_exp2f(sacc[j][mt][1]);
                float e2 = __builtin_amdgcn_exp2f(sacc[j][mt][2]);
                float e3 = __builtin_amdgcn_exp2f(sacc[j][mt][3]);
                lp += (e0 + e1) + (e2 + e3);
                uint2 pw = { pack2bf(e0, e1), pack2bf(e2, e3) };
                *(uint2*)(&Ps[prow + mt * 16 + g * 4]) = pw;
            }
            lacc[j] += lp;
        }
        __builtin_amdgcn_sched_barrier(0);

        __builtin_amdgcn_s_setprio(1);
        #pragma unroll
        for (int s2 = 0; s2 < 2; s2++) {
            bf16x8 pf0 = *(const bf16x8*)(&Ps[(qb +      c) * 72 + s2 * 32 + g * 8]);
            bf16x8 pf1 = *(const bf16x8*)(&Ps[(qb + 16 + c) * 72 + s2 * 32 + g * 8]);
            #pragma unroll
            for (int mtv = 0; mtv < 4; mtv++) {
                bf16x8 vf = *(const bf16x8*)(&Vts[(mtv * 16 + c) * 72 + s2 * 32 + g * 8]);
                oacc[0][mtv] = __builtin_amdgcn_mfma_f32_16x16x32_bf16(vf, pf0, oacc[0][mtv], 0, 0, 0);
                oacc[1][mtv] = __builtin_amdgcn_mfma_f32_16x16x32_bf16(vf, pf1, oacc[1][mtv], 0, 0, 0);
            }
        }
        __builtin_amdgcn_s_setprio(0);

        if (pfv) {
            __syncthreads();
            *(int4*)(&Ks [ srow       * 72 + scc * 8]) = kr0;
            *(int4*)(&Ks [(srow + 32) * 72 + scc * 8]) = kr1;
            *(int4*)(&Vts[ srow       * 72 + scc * 8]) = vr0;
            *(int4*)(&Vts[(srow + 32) * 72 + scc * 8]) = vr1;
            if (tid < 16) ((float4*)bias_lds)[tid] = br;
            __syncthreads();
        }
    }

    __syncthreads();
    #pragma unroll
    for (int j = 0; j < 2; j++) {
        float l = lacc[j];
        l += __shfl_xor(l, 16);
        l += __shfl_xor(l, 32);
        float inv_ = 1.0f / l;
        int orow = (qb + j * 16 + c) * 72;
        #pragma unroll
        for (int mtv = 0; mtv < 4; mtv++) {
            uint2 ow = { pack2bf(oacc[j][mtv][0] * inv_, oacc[j][mtv][1] * inv_),
                         pack2bf(oacc[j][mtv][2] * inv_, oacc[j][mtv][3] * inv_) };
            *(uint2*)(&Ps[orow + mtv * 16 + g * 4]) = ow;
        }
    }
    __syncthreads();
    #pragma unroll
    for (int i = 0; i < 4; i++) {
        int idx = tid + i * 256, row = idx >> 3, cc = idx & 7;
        *(int4*)(O + (((size_t)(q0 + row) * NB + b_) << 10) + h_ * 64 + cc * 8)
            = *(const int4*)(&Ps[row * 72 + cc * 8]);
    }
}

// ---------------- output GEMM (m97 structure): Y = O(bf16) @ Wo^T -> fp32 ----------------
__global__ __launch_bounds__(256, 2)
void out_gemm(const short* __restrict__ A, const short* __restrict__ Bw, float* __restrict__ C)
{
    __shared__ __align__(16) short As[128*32];
    __shared__ __align__(16) short Bs[128*32];
    const int tid = threadIdx.x;
    const int lane = tid & 63, w = tid >> 6;
    const int wm = w >> 1, wn = w & 1;
    const int g = lane >> 4, c = lane & 15;
    const int m0 = blockIdx.x * 128, n0 = blockIdx.y * 128;

    const int l4 = lane >> 2, col8 = (lane & 3) * 8;
    const short* gA = A  + (size_t)(m0 + w*16 + l4) * EMB + col8;
    const short* gB = Bw + (size_t)(n0 + w*16 + l4) * EMB + col8;
    short* ldsA0 = &As[(w*16) * 32];
    short* ldsA1 = &As[(64 + w*16) * 32];
    short* ldsB0 = &Bs[(w*16) * 32];
    short* ldsB1 = &Bs[(64 + w*16) * 32];

    f32x4 acc[4][4] = {};
    for (int kt = 0; kt < EMB; kt += 32) {
        gld16(gA + kt,          ldsA0);
        gld16(gA + 64*EMB + kt, ldsA1);
        gld16(gB + kt,          ldsB0);
        gld16(gB + 64*EMB + kt, ldsB1);
        __syncthreads();
        bf16x8 a[4], b[4];
        #pragma unroll
        for (int mt = 0; mt < 4; mt++) a[mt] = *(const bf16x8*)(&As[(wm*64 + mt*16 + c) * 32 + g * 8]);
        #pragma unroll
        for (int nt = 0; nt < 4; nt++) b[nt] = *(const bf16x8*)(&Bs[(wn*64 + nt*16 + c) * 32 + g * 8]);
        #pragma unroll
        for (int mt = 0; mt < 4; mt++)
            #pragma unroll
            for (int nt = 0; nt < 4; nt++)
                acc[mt][nt] = __builtin_amdgcn_mfma_f32_16x16x32_bf16(a[mt], b[nt], acc[mt][nt], 0, 0, 0);
        __syncthreads();
    }
    #pragma unroll
    for (int mt = 0; mt < 4; mt++)
        #pragma unroll
        for (int nt = 0; nt < 4; nt++)
            #pragma unroll
            for (int r = 0; r < 4; r++) {
                int row = m0 + wm*64 + mt*16 + g*4 + r;
                int col = n0 + wn*64 + nt*16 + c;
                C[(size_t)row * EMB + col] = acc[mt][nt][r];
            }
}

extern "C" void kernel_launch(void* const* d_in, const int* in_sizes, int n_in,
                              void* d_out, int out_size, void* d_ws, size_t ws_size,
                              hipStream_t stream)
{
    const float* q    = (const float*)d_in[0];
    const float* k    = (const float*)d_in[1];
    const float* v    = (const float*)d_in[2];
    const int*   mask = (const int*)  d_in[3];
    const float* Wq   = (const float*)d_in[4];
    const float* Wk   = (const float*)d_in[5];
    const float* Wv   = (const float*)d_in[6];
    const float* Wo   = (const float*)d_in[7];
    float* out = (float*)d_out;

    char* ws = (char*)d_ws;
    short* Wbf    = (short*)(ws);                    //  8,388,608 B
    short* Qws    = (short*)(ws +  8388608);         // 16,777,216 B (B,H,T,64)
    short* Kc     = (short*)(ws + 25165824);         // 16,777,216 B (B,H,i,64) compacted (proj z=1)
    short* Vws    = (short*)(ws + 41943040);         // 16,777,216 B dense V (proj z=2)
    short* Vtc    = (short*)(ws + 58720256);         // 16,777,216 B (B,H,64,i) compacted+transposed (gather_v)
    short* Ows    = (short*)(ws + 75497472);         // 16,777,216 B (T,B,E)
    float* bias_c = (float*)(ws + 92274688);         //     32,768 B
    short* Xvbf   = (short*)(ws + 92307456);         // 16,777,216 B
    int*   idxc   = (int*)  (ws + 109084672);        //     32,768 B
    int*   npad   = (int*)  (ws + 109117440);        //         64 B
    int*   inv    = (int*)  (ws + 109117504);        //     32,768 B
    // aliases (lifetimes disjoint): Xq_bf shares Ows (attn writes it later);
    // Xk_bf shares Vtc (written later by gather_v). Kc dedicated (written during proj).
    short* Xqbf = Ows;
    short* Xkbf = Vtc;

    prep_scan<<<PREP_BLOCKS + NB, 256, 0, stream>>>(q, k, v, Wq, Wk, Wv, Wo,
                                                    Wbf, Xqbf, Xkbf, Xvbf,
                                                    mask, idxc, inv, bias_c, npad);
    proj_gemm8<<<dim3(ROWS/256, EMB/256, 3), 512, 0, stream>>>(Xqbf, Xkbf, Xvbf, Wbf, inv,
                                                               Qws, Kc, Vws);
    gather_v<<<dim3(TSEQ/64, NB*NH), 256, 0, stream>>>(Vws, idxc, npad, Vtc);
    attn_kernel<<<dim3(TSEQ/128, NB*NH), 256, 0, stream>>>(Qws, Kc, Vtc, bias_c, npad, Ows);
    out_gemm<<<dim3(ROWS/128, EMB/128), 256, 0, stream>>>(Ows, Wbf + (size_t)3*EMB*EMB, out);
}

// Round 8
// 306.840 us; speedup vs baseline: 1.0802x; 1.0802x over previous
//
#include <hip/hip_runtime.h>
#include <stdint.h>

#define TSEQ 2048
#define NB   4
#define NH   16
#define HD   64
#define EMB  1024
#define ROWS (TSEQ*NB)   // 8192
#define NKT  (EMB/64)    // 16 K-tiles for the projection GEMM
#define PREP_BLOCKS 28672

typedef __attribute__((ext_vector_type(8))) short bf16x8;
typedef __attribute__((ext_vector_type(4))) short bf16x4;
typedef __attribute__((ext_vector_type(4))) float f32x4;

__device__ __forceinline__ short f2bf(float x) {
    uint32_t u = __builtin_bit_cast(uint32_t, x);
    u += 0x7fffu + ((u >> 16) & 1u);     // RNE
    return (short)(u >> 16);
}

__device__ __forceinline__ uint32_t pack2bf(float a, float b) {
    uint32_t ua = __builtin_bit_cast(uint32_t, a) + 0x8000u;
    uint32_t ub = __builtin_bit_cast(uint32_t, b) + 0x8000u;
    return (ua >> 16) | (ub & 0xffff0000u);
}

// async global->LDS, 16B per lane; lds ptr must be wave-uniform (lane i lands at lds + i*16)
__device__ __forceinline__ void gld16(const void* g, void* l) {
    __builtin_amdgcn_global_load_lds(
        (const __attribute__((address_space(1))) void*)g,
        (__attribute__((address_space(3))) void*)l,
        16, 0, 0);
}

// ---------------- prep + scan fused ----------------
// blocks [0, PREP_BLOCKS): fp32->bf16 conversion of [Wq,Wk,Wv,Wo | q,k,v].
// blocks [PREP_BLOCKS, PREP_BLOCKS+NB): per-batch key compaction scan ->
// idxc[b][i] = t of i-th valid key, inv[b][t] = i (or -1 masked),
// bias_c (-12 valid / -1e9 pad), npad[b].
__global__ __launch_bounds__(256)
void prep_scan(const float* __restrict__ q, const float* __restrict__ k, const float* __restrict__ v,
               const float* __restrict__ Wq, const float* __restrict__ Wk,
               const float* __restrict__ Wv, const float* __restrict__ Wo,
               short* __restrict__ Wbf,
               short* __restrict__ Xq, short* __restrict__ Xk, short* __restrict__ Xv,
               const int* __restrict__ mask, int* __restrict__ idxc, int* __restrict__ inv,
               float* __restrict__ bias_c, int* __restrict__ npad)
{
    __shared__ int sums[256];
    __shared__ int totalv;
    const int bid = blockIdx.x, tid = threadIdx.x;

    if (bid < PREP_BLOCKS) {
        int gid = bid * 256 + tid;
        const float4* s4;
        bf16x4* d4;
        if (gid < (1 << 20)) {
            int wsel = gid >> 18;
            const float* src = (wsel == 0) ? Wq : (wsel == 1) ? Wk : (wsel == 2) ? Wv : Wo;
            s4 = (const float4*)src + (gid & ((1 << 18) - 1));
            d4 = (bf16x4*)Wbf + gid;
        } else {
            int iid = gid - (1 << 20);
            int isel = iid >> 21, o = iid & ((1 << 21) - 1);
            const float* src = (isel == 0) ? q : (isel == 1) ? k : v;
            short* dst = (isel == 0) ? Xq : (isel == 1) ? Xk : Xv;
            s4 = (const float4*)src + o;
            d4 = (bf16x4*)dst + o;
        }
        float4 vv = *s4;
        bf16x4 o4 = { f2bf(vv.x), f2bf(vv.y), f2bf(vv.z), f2bf(vv.w) };
        *d4 = o4;
        return;
    }

    // ---- scan part ----
    const int b = bid - PREP_BLOCKS;
    const int* mb = mask + b * TSEQ;
    int valid[8]; int cnt = 0;
    #pragma unroll
    for (int j = 0; j < 8; j++) { valid[j] = (mb[tid * 8 + j] == 0); cnt += valid[j]; }
    sums[tid] = cnt;
    __syncthreads();
    for (int off = 1; off < 256; off <<= 1) {   // Hillis-Steele inclusive scan
        int vv = (tid >= off) ? sums[tid - off] : 0;
        __syncthreads();
        sums[tid] += vv;
        __syncthreads();
    }
    if (tid == 255) totalv = sums[255];
    int base = sums[tid] - cnt;
    __syncthreads();
    int nv = totalv;
    #pragma unroll
    for (int j = 0; j < 8; j++) {
        int t = tid * 8 + j;
        if (valid[j]) { idxc[b * TSEQ + base] = t; inv[b * TSEQ + t] = base; base++; }
        else          { inv[b * TSEQ + t] = -1; }
    }
    for (int i = tid; i < TSEQ; i += 256) {
        if (i >= nv) idxc[b * TSEQ + i] = 0;
        bias_c[b * TSEQ + i] = (i < nv) ? -12.0f : -1e9f;
    }
    if (tid == 0) npad[b] = (nv + 63) & ~63;
}

// ---------------- projection GEMM: 256x256 tile, snake 4-phase schedule ----------------
// C = X @ W^T, all bf16. 512 threads = 8 waves (2M x 4N, interleaved ownership).
// MEASURED-BEST CONFIG (proj=67.5us, WRITE=41MB):
//   dense sequential staging (idxc-gathered staging = latency-bound, -10%);
//   z=1 K epilogue scatter-compacts rows via inv (full-line writes: lanes span dk);
//   z=0/z=2 dense epilogue (V transpose scatter = write-amplification, -20%);
//   separate gather_v kernel is CHEAPER than fusing V-transpose here.
// Snake quadrant order (0,0)->(0,1)->(1,1)->(1,0): each phase reads ONE fresh operand
// subtile, holding the other in regs -> 24 ds_read/K-tile. One counted vmcnt(4)/K-tile.
// Register budget: acc fills 128 AGPRs; fragment live-set must stay <=128 VGPRs
// (launch_bounds(512,2) cap) -- deeper pipelining spills (round-3 regression).
// LDS XOR-swizzle byte ^= (row&7)<<4: pre-swizzled global src + swizzled ds_read.

#define DSA(MH)                                                                     \
    _Pragma("unroll")                                                               \
    for (int mf = 0; mf < 4; mf++) {                                                \
        _Pragma("unroll")                                                           \
        for (int ks = 0; ks < 2; ks++) {                                            \
            const int rr = wm*64 + mf*16 + c;                                       \
            const int cb = (ks*64 + g*16) ^ ((rr & 7) << 4);                        \
            af[mf][ks] = *(const bf16x8*)(&lds[cur][0][MH][0] + rr*64 + (cb >> 1)); \
        }                                                                           \
    }

#define DSB(NH_, DST)                                                               \
    _Pragma("unroll")                                                               \
    for (int nf = 0; nf < 2; nf++) {                                                \
        _Pragma("unroll")                                                           \
        for (int ks = 0; ks < 2; ks++) {                                            \
            const int rr = wn*32 + nf*16 + c;                                       \
            const int cb = (ks*64 + g*16) ^ ((rr & 7) << 4);                        \
            DST[nf][ks] = *(const bf16x8*)(&lds[cur][1][NH_][0] + rr*64 + (cb >> 1));\
        }                                                                           \
    }

#define MM(MH, NH_, BREG)                                                           \
    __builtin_amdgcn_s_barrier();                                                   \
    asm volatile("s_waitcnt lgkmcnt(0)" ::: "memory");                              \
    __builtin_amdgcn_sched_barrier(0);                                              \
    __builtin_amdgcn_s_setprio(1);                                                  \
    _Pragma("unroll")                                                               \
    for (int mf = 0; mf < 4; mf++) {                                                \
        _Pragma("unroll")                                                           \
        for (int nf = 0; nf < 2; nf++) {                                            \
            acc[MH][NH_][mf][nf] = __builtin_amdgcn_mfma_f32_16x16x32_bf16(         \
                af[mf][0], BREG[nf][0], acc[MH][NH_][mf][nf], 0, 0, 0);             \
            acc[MH][NH_][mf][nf] = __builtin_amdgcn_mfma_f32_16x16x32_bf16(         \
                af[mf][1], BREG[nf][1], acc[MH][NH_][mf][nf], 0, 0, 0);             \
        }                                                                           \
    }                                                                               \
    __builtin_amdgcn_s_setprio(0);                                                  \
    __builtin_amdgcn_sched_barrier(0);

__global__ __launch_bounds__(512, 2)
void proj_gemm8(const short* __restrict__ Xq, const short* __restrict__ Xk, const short* __restrict__ Xv,
                const short* __restrict__ Wbf, const int* __restrict__ inv,
                short* __restrict__ Qw, short* __restrict__ Kc, short* __restrict__ Vw)
{
    __shared__ __align__(16) short lds[2][2][2][128*64];   // [buf][A/B][half][row*64+col]
    const int z = blockIdx.z;
    const short* __restrict__ A  = (z == 0) ? Xq : (z == 1) ? Xk : Xv;
    const short* __restrict__ Bw = Wbf + (size_t)z * (EMB*EMB);
    short* __restrict__ dst = (z == 0) ? Qw : (z == 1) ? Kc : Vw;
    // Q scale: 1/sqrt(64) * log2(e)  (attention softmax runs in exp2 domain)
    const float scale = (z == 0) ? 0.18033688011112042f : 1.0f;

    const int tid = threadIdx.x;
    const int lane = tid & 63, w = tid >> 6;
    const int wm = w >> 2, wn = w & 3;          // wave owns rows {wm*64, 128+wm*64}, cols {wn*32, 128+wn*32}
    const int g = lane >> 4, c = lane & 15;
    const int m0 = blockIdx.x * 256, n0 = blockIdx.y * 256;

    const short* a0 = A  + (size_t)m0 * EMB;           // A half0: rows m0..m0+127
    const short* a1 = a0 + (size_t)128 * EMB;          // A half1
    const short* b0 = Bw + (size_t)n0 * EMB;           // B half0: W rows n0..n0+127
    const short* b1 = b0 + (size_t)128 * EMB;

    // stage one half-tile (128 rows x 64 cols bf16) cooperatively: 2 gld16 per thread.
    // LDS dest is linear (wave-uniform base + lane*16); source is pre-swizzled so that
    // the ds_read-side XOR (row&7)<<4 recovers the logical element (rule #21).
    auto stage = [&](const short* grow, short* lhalf) {
        #pragma unroll
        for (int p = 0; p < 2; p++) {
            const int lin = p * 8192 + w * 1024 + lane * 16;     // byte offset in half
            const int rin = lin >> 7;                            // row 0..127
            const int cb  = (lin & 127) ^ ((rin & 7) << 4);      // swizzled source col (bytes)
            gld16(grow + (size_t)rin * EMB + (cb >> 1), lhalf + p * 4096 + w * 512);
        }
    };

    // prologue: K-tile 0 fully + A0/B0 of K-tile 1 (matches steady-state issue pattern)
    stage(a0,      &lds[0][0][0][0]);
    stage(a1,      &lds[0][0][1][0]);
    stage(b0,      &lds[0][1][0][0]);
    stage(b1,      &lds[0][1][1][0]);
    stage(a0 + 64, &lds[1][0][0][0]);
    stage(b0 + 64, &lds[1][1][0][0]);
    asm volatile("s_waitcnt vmcnt(4)" ::: "memory");
    __builtin_amdgcn_s_barrier();

    f32x4 acc[2][2][4][2] = {};   // [mh][nh][mf][nf]

    // Phase stages: p0 -> A1[t+1], p1 -> B1[t+1], p2 -> A0[t+2], p3 -> B0[t+2].
    // vmcnt(4) at p3 leaves only {A0[t+2], B0[t+2]} in flight -> all of t+1 landed.
    #pragma unroll 2
    for (int t = 0; t < NKT; t++) {
        const int cur = t & 1, nxt = cur ^ 1;
        const int k1 = (t + 1 < NKT ? t + 1 : NKT - 1) * 64;   // clamped tail stages are
        const int k2 = (t + 2 < NKT ? t + 2 : NKT - 1) * 64;   // redundant writes, harmless
        bf16x8 af[4][2], b0r[2][2], b1r[2][2];
        // p0: quadrant (0,0) — fresh A0 + B0
        DSA(0); DSB(0, b0r);
        stage(a1 + k1, &lds[nxt][0][1][0]);
        MM(0, 0, b0r)
        __builtin_amdgcn_s_barrier();
        // p1: quadrant (0,1) — reuse A0, fresh B1
        DSB(1, b1r);
        stage(b1 + k1, &lds[nxt][1][1][0]);
        MM(0, 1, b1r)
        __builtin_amdgcn_s_barrier();
        // p2: quadrant (1,1) — fresh A1, reuse B1
        DSA(1);
        stage(a0 + k2, &lds[cur][0][0][0]);
        MM(1, 1, b1r)
        __builtin_amdgcn_s_barrier();
        // p3: quadrant (1,0) — reuse A1 + B0 (pure-MFMA phase)
        stage(b0 + k2, &lds[cur][1][0][0]);
        MM(1, 0, b0r)
        asm volatile("s_waitcnt vmcnt(4)" ::: "memory");
        __builtin_amdgcn_s_barrier();
    }
    asm volatile("s_waitcnt vmcnt(0)" ::: "memory");

    // epilogue: permuted store to (B,H,T,64) bf16.
    // z==1: scatter rows through inv[b][t] (compacted K); masked rows skipped.
    if (z == 1) {
        #pragma unroll
        for (int mh = 0; mh < 2; mh++)
            #pragma unroll
            for (int nh = 0; nh < 2; nh++)
                #pragma unroll
                for (int mf = 0; mf < 4; mf++)
                    #pragma unroll
                    for (int nf = 0; nf < 2; nf++)
                        #pragma unroll
                        for (int r = 0; r < 4; r++) {
                            int row = m0 + mh*128 + wm*64 + mf*16 + g*4 + r;
                            int col = n0 + nh*128 + wn*32 + nf*16 + c;
                            int tq = row >> 2, bb = row & 3, h = col >> 6, dk = col & 63;
                            int i = inv[bb * TSEQ + tq];
                            if (i >= 0)
                                dst[(((size_t)(bb*16 + h) * TSEQ + i) << 6) + dk]
                                    = f2bf(acc[mh][nh][mf][nf][r]);
                        }
    } else {
        #pragma unroll
        for (int mh = 0; mh < 2; mh++)
            #pragma unroll
            for (int nh = 0; nh < 2; nh++)
                #pragma unroll
                for (int mf = 0; mf < 4; mf++)
                    #pragma unroll
                    for (int nf = 0; nf < 2; nf++)
                        #pragma unroll
                        for (int r = 0; r < 4; r++) {
                            int row = m0 + mh*128 + wm*64 + mf*16 + g*4 + r;
                            int col = n0 + nh*128 + wn*32 + nf*16 + c;
                            int tq = row >> 2, bb = row & 3, h = col >> 6, dk = col & 63;
                            dst[(((size_t)(bb*16 + h) * TSEQ + tq) << 6) + dk]
                                = f2bf(acc[mh][nh][mf][nf][r] * scale);
                        }
    }
}

// ---------------- gather: V compaction + transpose (K handled in proj epilogue) ----------------
__global__ __launch_bounds__(256)
void gather_v(const short* __restrict__ V,
              const int* __restrict__ idxc, const int* __restrict__ npad,
              short* __restrict__ Vtc)
{
    const int bh = blockIdx.y, b = bh >> 4;
    const int i0 = blockIdx.x * 64;
    if (i0 >= npad[b]) return;
    __shared__ __align__(16) short tile[64*72];
    __shared__ int sidx[64];
    const int tid = threadIdx.x;
    if (tid < 64) sidx[tid] = idxc[b * TSEQ + i0 + tid];
    __syncthreads();
    const short* __restrict__ Vh = V + (size_t)bh * TSEQ * HD;
    #pragma unroll
    for (int p = 0; p < 2; p++) {
        int idx = tid + p * 256, row = idx >> 3, cc = idx & 7;
        int src = sidx[row];
        *(int4*)(&tile[row * 72 + cc * 8]) = *(const int4*)(Vh + (size_t)src * HD + cc * 8);
    }
    __syncthreads();
    #pragma unroll
    for (int p = 0; p < 2; p++) {
        int idx = tid + p * 256, dv = idx >> 3, cc = idx & 7;
        bf16x8 o;
        #pragma unroll
        for (int j = 0; j < 8; j++) o[j] = tile[(cc * 8 + j) * 72 + dv];
        *(bf16x8*)(Vtc + ((size_t)bh * HD + dv) * TSEQ + i0 + cc * 8) = o;
    }
}

// ---------------- flash attention v5: compacted keys, dynamic per-batch bound ----------------
// __launch_bounds__(256,3): the measured-safe occupancy. (256,4) capped VGPR at 64 ->
// mass spill (attn 89.8us, WRITE 151MB) -- round-7 regression, do not raise again.
__global__ __launch_bounds__(256, 3)
void attn_kernel(const short* __restrict__ Q, const short* __restrict__ K,
                 const short* __restrict__ Vt, const float* __restrict__ bias,
                 const int* __restrict__ npad,
                 short* __restrict__ O)
{
    __shared__ __align__(16) short Ks [64*72];    // [tk][d]
    __shared__ __align__(16) short Vts[64*72];    // [dv][tk]
    __shared__ __align__(16) short Ps [128*72];   // [q_local][tk]
    __shared__ __align__(16) float bias_lds[64];

    const int bh = blockIdx.y;
    const int b_ = bh >> 4, h_ = bh & 15;
    const int q0 = blockIdx.x * 128;
    const int tid = threadIdx.x, lane = tid & 63, wv = tid >> 6;
    const int g = lane >> 4, c = lane & 15;
    const int qb = wv * 32;
    const short* __restrict__ Qh  = Q  + (size_t)bh * TSEQ * HD;
    const short* __restrict__ Kh  = K  + (size_t)bh * TSEQ * HD;
    const short* __restrict__ Vth = Vt + (size_t)bh * HD * TSEQ;
    const float* __restrict__ biasb = bias + b_ * TSEQ;
    const int nit = npad[b_] >> 6;   // compacted+padded key count / 64

    const int srow = tid >> 3, scc = tid & 7;

    *(int4*)(&Ks [ srow       * 72 + scc * 8]) = *(const int4*)(Kh  + (size_t) srow       * HD + scc * 8);
    *(int4*)(&Ks [(srow + 32) * 72 + scc * 8]) = *(const int4*)(Kh  + (size_t)(srow + 32) * HD + scc * 8);
    *(int4*)(&Vts[ srow       * 72 + scc * 8]) = *(const int4*)(Vth + (size_t) srow       * TSEQ + scc * 8);
    *(int4*)(&Vts[(srow + 32) * 72 + scc * 8]) = *(const int4*)(Vth + (size_t)(srow + 32) * TSEQ + scc * 8);
    if (tid < 16) ((float4*)bias_lds)[tid] = ((const float4*)biasb)[tid];

    bf16x8 qf[2][2];
    #pragma unroll
    for (int j = 0; j < 2; j++)
        #pragma unroll
        for (int ks = 0; ks < 2; ks++)
            qf[j][ks] = *(const bf16x8*)(Qh + (size_t)(q0 + qb + j * 16 + c) * HD + ks * 32 + g * 8);
    __syncthreads();

    float lacc[2] = { 0.0f, 0.0f };
    f32x4 oacc[2][4] = {};

    for (int it = 0; it < nit; it++) {
        f32x4 sacc[2][4];
        #pragma unroll
        for (int mt = 0; mt < 4; mt++) {
            f32x4 bv = *(const f32x4*)(&bias_lds[mt * 16 + g * 4]);
            sacc[0][mt] = bv; sacc[1][mt] = bv;
        }

        int4 kr0, kr1, vr0, vr1; float4 br;
        const bool pfv = (it + 1 < nit);
        if (pfv) {
            int tk0n = (it + 1) * 64;
            kr0 = *(const int4*)(Kh  + (size_t)(tk0n + srow)      * HD + scc * 8);
            kr1 = *(const int4*)(Kh  + (size_t)(tk0n + srow + 32) * HD + scc * 8);
            vr0 = *(const int4*)(Vth + (size_t) srow       * TSEQ + tk0n + scc * 8);
            vr1 = *(const int4*)(Vth + (size_t)(srow + 32) * TSEQ + tk0n + scc * 8);
            if (tid < 16) br = ((const float4*)(biasb + tk0n))[tid];
        }

        __builtin_amdgcn_s_setprio(1);
        #pragma unroll
        for (int ks = 0; ks < 2; ks++)
            #pragma unroll
            for (int mt = 0; mt < 4; mt++) {
                bf16x8 kf = *(const bf16x8*)(&Ks[(mt * 16 + c) * 72 + ks * 32 + g * 8]);
                sacc[0][mt] = __builtin_amdgcn_mfma_f32_16x16x32_bf16(kf, qf[0][ks], sacc[0][mt], 0, 0, 0);
                sacc[1][mt] = __builtin_amdgcn_mfma_f32_16x16x32_bf16(kf, qf[1][ks], sacc[1][mt], 0, 0, 0);
            }
        __builtin_amdgcn_s_setprio(0);

        #pragma unroll
        for (int j = 0; j < 2; j++) {
            int prow = (qb + j * 16 + c) * 72;
            float lp = 0.0f;
            #pragma unroll
            for (int mt = 0; mt < 4; mt++) {
                float e0 = __builtin_amdgcn_exp2f(sacc[j][mt][0]);
                float e1 = __builtin_amdgcn_exp2f(sacc[j][mt][1]);
                float e2 = __builtin_amdgcn_exp2f(sacc[j][mt][2]);
                float e3 = __builtin_amdgcn_exp2f(sacc[j][mt][3]);
                lp += (e0 + e1) + (e2 + e3);
                uint2 pw = { pack2bf(e0, e1), pack2bf(e2, e3) };
                *(uint2*)(&Ps[prow + mt * 16 + g * 4]) = pw;
            }
            lacc[j] += lp;
        }
        __builtin_amdgcn_sched_barrier(0);

        __builtin_amdgcn_s_setprio(1);
        #pragma unroll
        for (int s2 = 0; s2 < 2; s2++) {
            bf16x8 pf0 = *(const bf16x8*)(&Ps[(qb +      c) * 72 + s2 * 32 + g * 8]);
            bf16x8 pf1 = *(const bf16x8*)(&Ps[(qb + 16 + c) * 72 + s2 * 32 + g * 8]);
            #pragma unroll
            for (int mtv = 0; mtv < 4; mtv++) {
                bf16x8 vf = *(const bf16x8*)(&Vts[(mtv * 16 + c) * 72 + s2 * 32 + g * 8]);
                oacc[0][mtv] = __builtin_amdgcn_mfma_f32_16x16x32_bf16(vf, pf0, oacc[0][mtv], 0, 0, 0);
                oacc[1][mtv] = __builtin_amdgcn_mfma_f32_16x16x32_bf16(vf, pf1, oacc[1][mtv], 0, 0, 0);
            }
        }
        __builtin_amdgcn_s_setprio(0);

        if (pfv) {
            __syncthreads();
            *(int4*)(&Ks [ srow       * 72 + scc * 8]) = kr0;
            *(int4*)(&Ks [(srow + 32) * 72 + scc * 8]) = kr1;
            *(int4*)(&Vts[ srow       * 72 + scc * 8]) = vr0;
            *(int4*)(&Vts[(srow + 32) * 72 + scc * 8]) = vr1;
            if (tid < 16) ((float4*)bias_lds)[tid] = br;
            __syncthreads();
        }
    }

    __syncthreads();
    #pragma unroll
    for (int j = 0; j < 2; j++) {
        float l = lacc[j];
        l += __shfl_xor(l, 16);
        l += __shfl_xor(l, 32);
        float inv_ = 1.0f / l;
        int orow = (qb + j * 16 + c) * 72;
        #pragma unroll
        for (int mtv = 0; mtv < 4; mtv++) {
            uint2 ow = { pack2bf(oacc[j][mtv][0] * inv_, oacc[j][mtv][1] * inv_),
                         pack2bf(oacc[j][mtv][2] * inv_, oacc[j][mtv][3] * inv_) };
            *(uint2*)(&Ps[orow + mtv * 16 + g * 4]) = ow;
        }
    }
    __syncthreads();
    #pragma unroll
    for (int i = 0; i < 4; i++) {
        int idx = tid + i * 256, row = idx >> 3, cc = idx & 7;
        *(int4*)(O + (((size_t)(q0 + row) * NB + b_) << 10) + h_ * 64 + cc * 8)
            = *(const int4*)(&Ps[row * 72 + cc * 8]);
    }
}

// ---------------- output GEMM (m97 structure): Y = O(bf16) @ Wo^T -> fp32 ----------------
__global__ __launch_bounds__(256, 2)
void out_gemm(const short* __restrict__ A, const short* __restrict__ Bw, float* __restrict__ C)
{
    __shared__ __align__(16) short As[128*32];
    __shared__ __align__(16) short Bs[128*32];
    const int tid = threadIdx.x;
    const int lane = tid & 63, w = tid >> 6;
    const int wm = w >> 1, wn = w & 1;
    const int g = lane >> 4, c = lane & 15;
    const int m0 = blockIdx.x * 128, n0 = blockIdx.y * 128;

    const int l4 = lane >> 2, col8 = (lane & 3) * 8;
    const short* gA = A  + (size_t)(m0 + w*16 + l4) * EMB + col8;
    const short* gB = Bw + (size_t)(n0 + w*16 + l4) * EMB + col8;
    short* ldsA0 = &As[(w*16) * 32];
    short* ldsA1 = &As[(64 + w*16) * 32];
    short* ldsB0 = &Bs[(w*16) * 32];
    short* ldsB1 = &Bs[(64 + w*16) * 32];

    f32x4 acc[4][4] = {};
    for (int kt = 0; kt < EMB; kt += 32) {
        gld16(gA + kt,          ldsA0);
        gld16(gA + 64*EMB + kt, ldsA1);
        gld16(gB + kt,          ldsB0);
        gld16(gB + 64*EMB + kt, ldsB1);
        __syncthreads();
        bf16x8 a[4], b[4];
        #pragma unroll
        for (int mt = 0; mt < 4; mt++) a[mt] = *(const bf16x8*)(&As[(wm*64 + mt*16 + c) * 32 + g * 8]);
        #pragma unroll
        for (int nt = 0; nt < 4; nt++) b[nt] = *(const bf16x8*)(&Bs[(wn*64 + nt*16 + c) * 32 + g * 8]);
        #pragma unroll
        for (int mt = 0; mt < 4; mt++)
            #pragma unroll
            for (int nt = 0; nt < 4; nt++)
                acc[mt][nt] = __builtin_amdgcn_mfma_f32_16x16x32_bf16(a[mt], b[nt], acc[mt][nt], 0, 0, 0);
        __syncthreads();
    }
    #pragma unroll
    for (int mt = 0; mt < 4; mt++)
        #pragma unroll
        for (int nt = 0; nt < 4; nt++)
            #pragma unroll
            for (int r = 0; r < 4; r++) {
                int row = m0 + wm*64 + mt*16 + g*4 + r;
                int col = n0 + wn*64 + nt*16 + c;
                C[(size_t)row * EMB + col] = acc[mt][nt][r];
            }
}

extern "C" void kernel_launch(void* const* d_in, const int* in_sizes, int n_in,
                              void* d_out, int out_size, void* d_ws, size_t ws_size,
                              hipStream_t stream)
{
    const float* q    = (const float*)d_in[0];
    const float* k    = (const float*)d_in[1];
    const float* v    = (const float*)d_in[2];
    const int*   mask = (const int*)  d_in[3];
    const float* Wq   = (const float*)d_in[4];
    const float* Wk   = (const float*)d_in[5];
    const float* Wv   = (const float*)d_in[6];
    const float* Wo   = (const float*)d_in[7];
    float* out = (float*)d_out;

    char* ws = (char*)d_ws;
    short* Wbf    = (short*)(ws);                    //  8,388,608 B
    short* Qws    = (short*)(ws +  8388608);         // 16,777,216 B (B,H,T,64)
    short* Kc     = (short*)(ws + 25165824);         // 16,777,216 B (B,H,i,64) compacted (proj z=1)
    short* Vws    = (short*)(ws + 41943040);         // 16,777,216 B dense V (proj z=2)
    short* Vtc    = (short*)(ws + 58720256);         // 16,777,216 B (B,H,64,i) compacted+transposed (gather_v)
    short* Ows    = (short*)(ws + 75497472);         // 16,777,216 B (T,B,E)
    float* bias_c = (float*)(ws + 92274688);         //     32,768 B
    short* Xvbf   = (short*)(ws + 92307456);         // 16,777,216 B
    int*   idxc   = (int*)  (ws + 109084672);        //     32,768 B
    int*   npad   = (int*)  (ws + 109117440);        //         64 B
    int*   inv    = (int*)  (ws + 109117504);        //     32,768 B
    // aliases (lifetimes disjoint): Xq_bf shares Ows (attn writes it later);
    // Xk_bf shares Vtc (written later by gather_v). Kc dedicated (written during proj).
    short* Xqbf = Ows;
    short* Xkbf = Vtc;

    prep_scan<<<PREP_BLOCKS + NB, 256, 0, stream>>>(q, k, v, Wq, Wk, Wv, Wo,
                                                    Wbf, Xqbf, Xkbf, Xvbf,
                                                    mask, idxc, inv, bias_c, npad);
    proj_gemm8<<<dim3(ROWS/256, EMB/256, 3), 512, 0, stream>>>(Xqbf, Xkbf, Xvbf, Wbf, inv,
                                                               Qws, Kc, Vws);
    gather_v<<<dim3(TSEQ/64, NB*NH), 256, 0, stream>>>(Vws, idxc, npad, Vtc);
    attn_kernel<<<dim3(TSEQ/128, NB*NH), 256, 0, stream>>>(Qws, Kc, Vtc, bias_c, npad, Ows);
    out_gemm<<<dim3(ROWS/128, EMB/128), 256, 0, stream>>>(Ows, Wbf + (size_t)3*EMB*EMB, out);
}